// Round 17
// baseline (1047.501 us; speedup 1.0000x reference)
//
#include <hip/hip_runtime.h>
#include <hip/hip_bf16.h>

// TensorConvLayer: edge MLP (bf16 MFMA) -> tensor product (in-register) ->
// ticketed sorted-row emit (1 int atomic/edge) -> coalesced node gather -> BN.
//
// R16 -> R17 (single change): R16 green at 837us edge, occupancy doubled to
// 44.8% but time only -19% -- atomic arithmetic shows the wall: 20.5M fp32
// atomics at ~24.5G/s (R1: 20.5G/s, same ceiling) with WRITE 515MB (~25B
// HBM per 4B atomic). Fix = R2's PROVEN ticketed sorted-row emit: 1 int
// atomic/edge + 160B coalesced fp32 row store into tp[roff[src]+ticket],
// R2's exact aux chain (zero/count/scan/node2), R2's exact ws layout
// (proven fit). Edge kernel otherwise identical to green R16.

typedef __bf16 bf16_t;
typedef bf16_t bf16x8 __attribute__((ext_vector_type(8)));
typedef bf16_t bf16x4 __attribute__((ext_vector_type(4)));
typedef float  f32x4  __attribute__((ext_vector_type(4)));

__device__ __forceinline__ bf16_t f2bf(float f) {
  unsigned u = __builtin_bit_cast(unsigned, f);
  u += 0x7fffu + ((u >> 16) & 1u);          // round-to-nearest-even
  unsigned short s = (unsigned short)(u >> 16);
  return __builtin_bit_cast(bf16_t, s);
}

#define MFMA16(a, b, c) __builtin_amdgcn_mfma_f32_16x16x32_bf16((a), (b), (c), 0, 0, 0)

// ---------------------------------------------------------------- zero ----
__global__ __launch_bounds__(256) void tcl_zero(
    int* __restrict__ cnt, int* __restrict__ pos, float* __restrict__ stats, int NN)
{
  int t = blockIdx.x * 256 + threadIdx.x;
  if (t < NN) { cnt[t] = 0; pos[t] = 0; }
  if (t < 48) stats[t] = 0.f;
}

// ------------------------------------------------------- count + wprep ----
__global__ __launch_bounds__(256) void tcl_count(
    const int* __restrict__ eidx, const float* __restrict__ w1,
    const float* __restrict__ w2, unsigned short* __restrict__ w1tg,
    unsigned short* __restrict__ w2tg, int* __restrict__ cnt, int E)
{
  int t = blockIdx.x * 256 + threadIdx.x;
  if (t < E) atomicAdd(&cnt[eidx[E + t]], 1);
  if (t < 64 * 64) {
    int k = t >> 6, n = t & 63;
    w1tg[n * 64 + k] = __builtin_bit_cast(unsigned short, f2bf(w1[t]));
  }
  if (t < 576 * 64) {
    int k = t / 576, n = t % 576;
    w2tg[n * 64 + k] = __builtin_bit_cast(unsigned short, f2bf(w2[t]));
  }
}

// ---------------------------------------------------------------- scan ----
__global__ __launch_bounds__(1024) void tcl_scan_a(
    const int* __restrict__ cnt, int* __restrict__ excl,
    int* __restrict__ bsum, int NN)
{
  __shared__ int sm[1024];
  int i = blockIdx.x * 1024 + threadIdx.x;
  int v = (i < NN) ? cnt[i] : 0;
  sm[threadIdx.x] = v;
  __syncthreads();
#pragma unroll
  for (int off = 1; off < 1024; off <<= 1) {
    int t = (threadIdx.x >= off) ? sm[threadIdx.x - off] : 0;
    __syncthreads();
    sm[threadIdx.x] += t;
    __syncthreads();
  }
  if (i < NN) excl[i] = sm[threadIdx.x] - v;
  if (threadIdx.x == 1023) bsum[blockIdx.x] = sm[threadIdx.x];
}

__global__ __launch_bounds__(128) void tcl_scan_b(int* __restrict__ bsum, int nb)
{
  __shared__ int sm[128];
  int t = threadIdx.x;
  int v = (t < nb) ? bsum[t] : 0;
  sm[t] = v;
  __syncthreads();
#pragma unroll
  for (int off = 1; off < 128; off <<= 1) {
    int u = (t >= off) ? sm[t - off] : 0;
    __syncthreads();
    sm[t] += u;
    __syncthreads();
  }
  if (t < nb) bsum[t] = sm[t] - v;
}

__global__ __launch_bounds__(256) void tcl_scan_c(
    const int* __restrict__ excl, const int* __restrict__ bsum,
    int* __restrict__ roff, int NN)
{
  int i = blockIdx.x * 256 + threadIdx.x;
  if (i < NN) roff[i] = excl[i] + bsum[i >> 10];
}

// ---------------------------------------------------------------- edge ----
// One wave = 16 edges. lane = kg*16 + l15: l15 = edge-in-group, kg = K-slice.
// SORTED: ticketed row write to tp. !SORTED: direct atomic scatter (R16).
template <bool SORTED>
__global__ __launch_bounds__(256) void tcl_edge(
    const float* __restrict__ atom, const float* __restrict__ efeat,
    const float* __restrict__ esh, const int* __restrict__ eidx,
    const float* __restrict__ b1, const float* __restrict__ b2,
    const unsigned short* __restrict__ w1tg, const unsigned short* __restrict__ w2tg,
    float* __restrict__ outbuf, int* __restrict__ pos,
    const int* __restrict__ roff, int* __restrict__ cnt, int E)
{
  // wave-private LDS slices -> no __syncthreads anywhere.
  __shared__ __attribute__((aligned(16))) bf16_t hlds[4][16][72];
  __shared__ __attribute__((aligned(16))) float  xg[4][16][68];

  const int tid  = threadIdx.x;
  const int wv   = tid >> 6;      // wave 0..3 (independent)
  const int lane = tid & 63;
  const int l15  = lane & 15;     // edge in group
  const int kg   = lane >> 4;     // K-slice 0..3
  const int kh   = kg >> 1;
  const bf16_t* w1b = (const bf16_t*)w1tg;
  const bf16_t* w2b = (const bf16_t*)w2tg;

  const int ngr = (E + 15) >> 4;
  const int gw0 = blockIdx.x * 4 + wv;
  const int gstride = gridDim.x * 4;

  for (int g = gw0; g < ngr; g += gstride) {
    long ge = (long)g * 16 + l15;
    bool v = ge < E;

    // ---- A: efeat -> B-fragments direct from global (full K=64 row) ----
    bf16x8 Bf0, Bf1;
    {
      float4 a = {0,0,0,0}, b = a, c = a, d = a;
      if (v) {
        const float4* p = (const float4*)(efeat + ge * 64 + kg * 8);
        a = p[0]; b = p[1];
        const float4* q = (const float4*)(efeat + ge * 64 + 32 + kg * 8);
        c = q[0]; d = q[1];
      }
      Bf0[0]=f2bf(a.x); Bf0[1]=f2bf(a.y); Bf0[2]=f2bf(a.z); Bf0[3]=f2bf(a.w);
      Bf0[4]=f2bf(b.x); Bf0[5]=f2bf(b.y); Bf0[6]=f2bf(b.z); Bf0[7]=f2bf(b.w);
      Bf1[0]=f2bf(c.x); Bf1[1]=f2bf(c.y); Bf1[2]=f2bf(c.z); Bf1[3]=f2bf(c.w);
      Bf1[4]=f2bf(d.x); Bf1[5]=f2bf(d.y); Bf1[6]=f2bf(d.z); Bf1[7]=f2bf(d.w);
    }

    // ---- B: premultiplied TP coefficient table (work split by kg) ----
    //  [0:16) x0 | [16:40) x1*sh0*c11 | [40:48) (x1.sh1)*c10
    //  [48:64) x0*sh0*c00 | [64:67) sh1*c01
    if (v) {
      int dst = eidx[ge];
      const float* xr = atom + (long)dst * 40;
      const float inv_s2 = 0.70710678118654752f;
      if (kg == 0) {
        for (int i = 0; i < 16; ++i) xg[wv][l15][i] = xr[i];
      } else if (kg == 1) {
        float k11 = esh[ge * 4] * inv_s2 * 0.35355339059327378f;
        for (int t2 = 0; t2 < 24; ++t2) xg[wv][l15][16 + t2] = xr[16 + t2] * k11;
      } else if (kg == 2) {
        float s1x = esh[ge * 4 + 1], s1y = esh[ge * 4 + 2], s1z = esh[ge * 4 + 3];
        float k10 = inv_s2 * 0.20412414523193150f;
        for (int i = 0; i < 8; ++i) {
          float y = xr[16 + 3 * i] * s1x + xr[17 + 3 * i] * s1y + xr[18 + 3 * i] * s1z;
          xg[wv][l15][40 + i] = y * k10;
        }
        float ks = inv_s2 * 0.25f;
        xg[wv][l15][64] = s1x * ks;
        xg[wv][l15][65] = s1y * ks;
        xg[wv][l15][66] = s1z * ks;
      } else {
        float k0s = esh[ge * 4] * inv_s2 * 0.25f;
        for (int i = 0; i < 16; ++i) xg[wv][l15][48 + i] = xr[i] * k0s;
      }
    }

    // ---- C: GEMM1  h[j][e] = relu(W1T . ef + b1), all 64 rows ----
    for (int mf = 0; mf < 4; ++mf) {
      const bf16_t* ap = w1b + (16 * mf + l15) * 64;
      bf16x8 a0 = *(const bf16x8*)(ap + kg * 8);
      bf16x8 a1 = *(const bf16x8*)(ap + 32 + kg * 8);
      f32x4 acc = {0.f, 0.f, 0.f, 0.f};
      acc = MFMA16(a0, Bf0, acc);
      acc = MFMA16(a1, Bf1, acc);
      int j0 = 16 * mf + 4 * kg;   // C/D: col=lane&15 (edge), row=(lane>>4)*4+r
      bf16x4 hv;
#pragma unroll
      for (int r = 0; r < 4; ++r) {
        float x = acc[r] + b1[j0 + r];
        x = x > 0.f ? x : 0.f;
        hv[r] = f2bf(x);
      }
      *(bf16x4*)&hlds[wv][l15][j0] = hv;
    }

    // ---- D: re-read h as B-fragments (same wave; lgkmcnt ordering) ----
    bf16x8 Bh0 = *(const bf16x8*)&hlds[wv][l15][kg * 8];
    bf16x8 Bh1 = *(const bf16x8*)&hlds[wv][l15][32 + kg * 8];
    float s0 = xg[wv][l15][64], s1 = xg[wv][l15][65], s2 = xg[wv][l15][66];

    // ---- E: GEMM2 (all 36 w-row blocks) fused with tensor product ----
    float o0[4] = {};        // out0 slice j = 4*kg + r (complete per lane)
    float o1[4][3] = {};     // out1 slice j = 4*(kg&1) + r (partial: this kh)
    for (int mf = 0; mf < 36; ++mf) {
      const bf16_t* ap = w2b + (16 * mf + l15) * 64;
      bf16x8 a0 = *(const bf16x8*)(ap + kg * 8);
      bf16x8 a1 = *(const bf16x8*)(ap + 32 + kg * 8);
      f32x4 bv = *(const f32x4*)&b2[16 * mf + 4 * kg];
      f32x4 acc = {0.f, 0.f, 0.f, 0.f};
      acc = MFMA16(a0, Bh0, acc);
      acc = MFMA16(a1, Bh1, acc);
      if (mf < 16) {                       // w00: i=mf, j=4*kg+r
        float cA = xg[wv][l15][48 + mf];
#pragma unroll
        for (int r = 0; r < 4; ++r) o0[r] += (acc[r] + bv[r]) * cA;
      } else if (mf < 20) {                // w11: i=2*(mf-16)+kh, j=4*(kg&1)+r
        int i = 2 * (mf - 16) + kh;
        float c0 = xg[wv][l15][16 + 3 * i], c1 = xg[wv][l15][17 + 3 * i], c2 = xg[wv][l15][18 + 3 * i];
#pragma unroll
        for (int r = 0; r < 4; ++r) {
          float wA = acc[r] + bv[r];
          o1[r][0] += wA * c0; o1[r][1] += wA * c1; o1[r][2] += wA * c2;
        }
      } else if (mf < 28) {                // w01: i=2*(mf-20)+kh, j=4*(kg&1)+r
        int i = 2 * (mf - 20) + kh;
        float xA = xg[wv][l15][i];
#pragma unroll
        for (int r = 0; r < 4; ++r) {
          float tA = (acc[r] + bv[r]) * xA;
          o1[r][0] += tA * s0; o1[r][1] += tA * s1; o1[r][2] += tA * s2;
        }
      } else {                             // w10: i=mf-28, j=4*kg+r
        float cA = xg[wv][l15][40 + mf - 28];
#pragma unroll
        for (int r = 0; r < 4; ++r) o0[r] += (acc[r] + bv[r]) * cA;
      }
    }
    // fold kh pairs (lane^32: kg<->kg^2, same l15); lanes kg<2 hold full o1
    float o1f[4][3];
#pragma unroll
    for (int r = 0; r < 4; ++r)
#pragma unroll
      for (int c = 0; c < 3; ++c)
        o1f[r][c] = o1[r][c] + __shfl_xor(o1[r][c], 32);

    // ---- F: emit ----
    if (SORTED) {
      // one int ticket per edge (kg==0 lane), broadcast row to kg-partners
      int dstrow = 0;
      if (v && kg == 0) {
        int src = eidx[E + ge];
        dstrow = roff[src] + atomicAdd(&pos[src], 1);
      }
      dstrow = __shfl(dstrow, l15);      // lane l15 holds kg==0's ticket
      if (v) {
        float* orow = outbuf + (long)dstrow * 40;
        f32x4 v0 = {o0[0], o0[1], o0[2], o0[3]};
        *(f32x4*)(orow + 4 * kg) = v0;
        if (kg < 2) {
          f32x4 u0 = {o1f[0][0], o1f[0][1], o1f[0][2], o1f[1][0]};
          f32x4 u1 = {o1f[1][1], o1f[1][2], o1f[2][0], o1f[2][1]};
          f32x4 u2 = {o1f[2][2], o1f[3][0], o1f[3][1], o1f[3][2]};
          float* ob = orow + 16 + 12 * kg;
          *(f32x4*)(ob + 0) = u0;
          *(f32x4*)(ob + 4) = u1;
          *(f32x4*)(ob + 8) = u2;
        }
      }
    } else {
      if (v) {
        int src = eidx[E + ge];
        float* srow = outbuf + (long)src * 40;
#pragma unroll
        for (int r = 0; r < 4; ++r) unsafeAtomicAdd(&srow[4 * kg + r], o0[r]);
        if (kg < 2) {
          int j1 = 4 * kg;
#pragma unroll
          for (int r = 0; r < 4; ++r)
#pragma unroll
            for (int c = 0; c < 3; ++c)
              unsafeAtomicAdd(&srow[16 + 3 * (j1 + r) + c], o1f[r][c]);
        }
      }
    }
  }
}

// -------------------------------------------------------- node (gather) ----
__global__ __launch_bounds__(256) void tcl_node2(
    const float* __restrict__ atom, const float* __restrict__ tp,
    const int* __restrict__ roff, const int* __restrict__ cnt,
    float* __restrict__ out, float* __restrict__ stats, int NN)
{
  int lane = threadIdx.x & 63;
  int gw = blockIdx.x * 4 + (threadIdx.x >> 6);
  int stride = gridDim.x * 4;
  float ssum = 0.f, ssq = 0.f, vsq = 0.f;
  for (int n = gw; n < NN; n += stride) {
    int deg = cnt[n];
    long base = roff[n];
    if (lane < 40) {
      float acc = 0.f;
      for (int d = 0; d < deg; ++d) acc += tp[(base + d) * 40 + lane];
      float c = deg > 0 ? (float)deg : 1.f;
      long idx = (long)n * 40 + lane;
      float o = acc / c + atom[idx];
      out[idx] = o;
      if (lane < 16) { ssum += o; ssq += o * o; }
      else           { vsq += o * o; }
    }
  }
  if (lane < 16) {
    unsafeAtomicAdd(&stats[lane], ssum);
    unsafeAtomicAdd(&stats[16 + lane], ssq);
  } else if (lane < 40) {
    unsafeAtomicAdd(&stats[32 + (lane - 16) / 3], vsq);
  }
}

// ---------------------------------------------------- node (atomic path) ----
__global__ __launch_bounds__(256) void tcl_node(
    const float* __restrict__ atom, const int* __restrict__ cnt,
    float* __restrict__ out, float* __restrict__ stats, int NN)
{
  int lane = threadIdx.x & 63;
  int gw = blockIdx.x * 4 + (threadIdx.x >> 6);
  int stride = gridDim.x * 4;
  float ssum = 0.f, ssq = 0.f, vsq = 0.f;
  for (int r = gw; r < NN; r += stride) {
    float c = (float)cnt[r];
    c = c > 1.f ? c : 1.f;
    if (lane < 40) {
      long idx = (long)r * 40 + lane;
      float o = out[idx] / c + atom[idx];
      out[idx] = o;
      if (lane < 16) { ssum += o; ssq += o * o; }
      else           { vsq += o * o; }
    }
  }
  if (lane < 16) {
    unsafeAtomicAdd(&stats[lane], ssum);
    unsafeAtomicAdd(&stats[16 + lane], ssq);
  } else if (lane < 40) {
    unsafeAtomicAdd(&stats[32 + (lane - 16) / 3], vsq);
  }
}

// ---------------------------------------------------------------- norm ----
__global__ __launch_bounds__(256) void tcl_norm(
    float* __restrict__ out, const float* __restrict__ stats,
    const float* __restrict__ bnw, const float* __restrict__ bnb, int NN)
{
  long idx = (long)blockIdx.x * 256 + threadIdx.x;
  long tot = (long)NN * 40;
  if (idx >= tot) return;
  int c = (int)(idx % 40);
  float o = out[idx];
  float invN = 1.0f / (float)NN;
  if (c < 16) {
    float mean = stats[c] * invN;
    float var  = stats[16 + c] * invN - mean * mean;
    float rs   = rsqrtf(var + 1e-5f);
    o = (o - mean) * rs * bnw[c] + bnb[c];
  } else {
    int m = (c - 16) / 3;
    float vn = stats[32 + m] * invN * (1.0f / 3.0f);
    float rs = rsqrtf(vn + 1e-5f);
    o = o * rs * bnw[16 + m];
  }
  out[idx] = o;
}

// -------------------------------------------------------------- launch ----
extern "C" void kernel_launch(void* const* d_in, const int* in_sizes, int n_in,
                              void* d_out, int out_size, void* d_ws, size_t ws_size,
                              hipStream_t stream)
{
  const float* atom  = (const float*)d_in[0];
  const float* efeat = (const float*)d_in[1];
  const float* esh   = (const float*)d_in[2];
  const int*   eidx  = (const int*)d_in[3];
  const float* w1    = (const float*)d_in[4];
  const float* b1    = (const float*)d_in[5];
  const float* w2    = (const float*)d_in[6];
  const float* b2    = (const float*)d_in[7];
  const float* bnw   = (const float*)d_in[8];
  const float* bnb   = (const float*)d_in[9];
  int E  = in_sizes[3] / 2;
  int NN = in_sizes[0] / 40;
  float* out = (float*)d_out;

  // workspace layout (R2's proven-fit layout: ~81.7MB for E=500k, NN=100k)
  size_t off = 0;
  auto align256 = [&](size_t o) { return (o + 255) & ~(size_t)255; };
  int* cnt = (int*)d_ws;                                   off += (size_t)NN * 4;
  off = align256(off);
  int* pos = (int*)((char*)d_ws + off);                    off += (size_t)NN * 4;
  off = align256(off);
  int* excl = (int*)((char*)d_ws + off);                   off += (size_t)NN * 4;
  off = align256(off);
  int* bsum = (int*)((char*)d_ws + off);                   off += 128 * 4;
  off = align256(off);
  int* roff = (int*)((char*)d_ws + off);                   off += (size_t)NN * 4;
  off = align256(off);
  float* stats = (float*)((char*)d_ws + off);              off += 48 * 4;
  off = align256(off);
  unsigned short* w1tg = (unsigned short*)((char*)d_ws + off); off += 64 * 64 * 2;
  off = align256(off);
  unsigned short* w2tg = (unsigned short*)((char*)d_ws + off); off += 576 * 64 * 2;
  off = align256(off);
  float* tp = (float*)((char*)d_ws + off);
  size_t need = off + (size_t)E * 40 * 4;

  int nb = (NN + 1023) / 1024;   // scan chunks (<=128)
  bool sorted = (ws_size >= need) && (nb <= 128);

  tcl_zero<<<(NN + 255) / 256, 256, 0, stream>>>(cnt, pos, stats, NN);
  tcl_count<<<(E + 255) / 256, 256, 0, stream>>>(eidx, w1, w2, w1tg, w2tg, cnt, E);

  if (sorted) {
    tcl_scan_a<<<nb, 1024, 0, stream>>>(cnt, excl, bsum, NN);
    tcl_scan_b<<<1, 128, 0, stream>>>(bsum, nb);
    tcl_scan_c<<<(NN + 255) / 256, 256, 0, stream>>>(excl, bsum, roff, NN);
    tcl_edge<true><<<2048, 256, 0, stream>>>(atom, efeat, esh, eidx, b1, b2,
                                             w1tg, w2tg, tp, pos, roff, cnt, E);
    tcl_node2<<<1024, 256, 0, stream>>>(atom, tp, roff, cnt, out, stats, NN);
  } else {
    hipMemsetAsync(d_out, 0, (size_t)NN * 40 * sizeof(float), stream);
    tcl_edge<false><<<2048, 256, 0, stream>>>(atom, efeat, esh, eidx, b1, b2,
                                              w1tg, w2tg, out, pos, roff, cnt, E);
    tcl_node<<<256, 256, 0, stream>>>(atom, cnt, out, stats, NN);
  }
  tcl_norm<<<(int)(((long)NN * 40 + 255) / 256), 256, 0, stream>>>(out, stats, bnw, bnb, NN);
}

// Round 18
// 484.250 us; speedup vs baseline: 2.1631x; 2.1631x over previous
//
#include <hip/hip_runtime.h>
#include <hip/hip_bf16.h>

// TensorConvLayer: edge MLP (bf16 MFMA) -> tensor product (in-register) ->
// ticketed sorted-row emit (1 int atomic/edge) -> coalesced node gather -> BN.
//
// R17 -> R18 (node2-only): R17 green; top kernel now tcl_node2 627us at
// 0.36% HBM -- BN-stats same-address atomic contention (4096 waves x 48
// addresses, 153ns/RMW measured). Fix: (1) stats striped into 32 replicas
// (contention /32), (2) in-wave 3:1 shfl fold of vsq (24->8 atomics/wave),
// (3) tiny collapse kernel sums replicas -> statsfin for norm. Edge kernel
// and all other machinery byte-identical to green R17.

typedef __bf16 bf16_t;
typedef bf16_t bf16x8 __attribute__((ext_vector_type(8)));
typedef bf16_t bf16x4 __attribute__((ext_vector_type(4)));
typedef float  f32x4  __attribute__((ext_vector_type(4)));

#define NREP 32   // stats replicas

__device__ __forceinline__ bf16_t f2bf(float f) {
  unsigned u = __builtin_bit_cast(unsigned, f);
  u += 0x7fffu + ((u >> 16) & 1u);          // round-to-nearest-even
  unsigned short s = (unsigned short)(u >> 16);
  return __builtin_bit_cast(bf16_t, s);
}

#define MFMA16(a, b, c) __builtin_amdgcn_mfma_f32_16x16x32_bf16((a), (b), (c), 0, 0, 0)

// ---------------------------------------------------------------- zero ----
__global__ __launch_bounds__(256) void tcl_zero(
    int* __restrict__ cnt, int* __restrict__ pos, float* __restrict__ statsrep,
    float* __restrict__ statsfin, int NN)
{
  int t = blockIdx.x * 256 + threadIdx.x;
  if (t < NN) { cnt[t] = 0; pos[t] = 0; }
  if (t < NREP * 64) statsrep[t] = 0.f;
  if (t < 64) statsfin[t] = 0.f;
}

// ------------------------------------------------------- count + wprep ----
__global__ __launch_bounds__(256) void tcl_count(
    const int* __restrict__ eidx, const float* __restrict__ w1,
    const float* __restrict__ w2, unsigned short* __restrict__ w1tg,
    unsigned short* __restrict__ w2tg, int* __restrict__ cnt, int E)
{
  int t = blockIdx.x * 256 + threadIdx.x;
  if (t < E) atomicAdd(&cnt[eidx[E + t]], 1);
  if (t < 64 * 64) {
    int k = t >> 6, n = t & 63;
    w1tg[n * 64 + k] = __builtin_bit_cast(unsigned short, f2bf(w1[t]));
  }
  if (t < 576 * 64) {
    int k = t / 576, n = t % 576;
    w2tg[n * 64 + k] = __builtin_bit_cast(unsigned short, f2bf(w2[t]));
  }
}

// ---------------------------------------------------------------- scan ----
__global__ __launch_bounds__(1024) void tcl_scan_a(
    const int* __restrict__ cnt, int* __restrict__ excl,
    int* __restrict__ bsum, int NN)
{
  __shared__ int sm[1024];
  int i = blockIdx.x * 1024 + threadIdx.x;
  int v = (i < NN) ? cnt[i] : 0;
  sm[threadIdx.x] = v;
  __syncthreads();
#pragma unroll
  for (int off = 1; off < 1024; off <<= 1) {
    int t = (threadIdx.x >= off) ? sm[threadIdx.x - off] : 0;
    __syncthreads();
    sm[threadIdx.x] += t;
    __syncthreads();
  }
  if (i < NN) excl[i] = sm[threadIdx.x] - v;
  if (threadIdx.x == 1023) bsum[blockIdx.x] = sm[threadIdx.x];
}

__global__ __launch_bounds__(128) void tcl_scan_b(int* __restrict__ bsum, int nb)
{
  __shared__ int sm[128];
  int t = threadIdx.x;
  int v = (t < nb) ? bsum[t] : 0;
  sm[t] = v;
  __syncthreads();
#pragma unroll
  for (int off = 1; off < 128; off <<= 1) {
    int u = (t >= off) ? sm[t - off] : 0;
    __syncthreads();
    sm[t] += u;
    __syncthreads();
  }
  if (t < nb) bsum[t] = sm[t] - v;
}

__global__ __launch_bounds__(256) void tcl_scan_c(
    const int* __restrict__ excl, const int* __restrict__ bsum,
    int* __restrict__ roff, int NN)
{
  int i = blockIdx.x * 256 + threadIdx.x;
  if (i < NN) roff[i] = excl[i] + bsum[i >> 10];
}

// ---------------------------------------------------------------- edge ----
// One wave = 16 edges. lane = kg*16 + l15: l15 = edge-in-group, kg = K-slice.
// SORTED: ticketed row write to tp. !SORTED: direct atomic scatter (R16).
template <bool SORTED>
__global__ __launch_bounds__(256) void tcl_edge(
    const float* __restrict__ atom, const float* __restrict__ efeat,
    const float* __restrict__ esh, const int* __restrict__ eidx,
    const float* __restrict__ b1, const float* __restrict__ b2,
    const unsigned short* __restrict__ w1tg, const unsigned short* __restrict__ w2tg,
    float* __restrict__ outbuf, int* __restrict__ pos,
    const int* __restrict__ roff, int* __restrict__ cnt, int E)
{
  // wave-private LDS slices -> no __syncthreads anywhere.
  __shared__ __attribute__((aligned(16))) bf16_t hlds[4][16][72];
  __shared__ __attribute__((aligned(16))) float  xg[4][16][68];

  const int tid  = threadIdx.x;
  const int wv   = tid >> 6;      // wave 0..3 (independent)
  const int lane = tid & 63;
  const int l15  = lane & 15;     // edge in group
  const int kg   = lane >> 4;     // K-slice 0..3
  const int kh   = kg >> 1;
  const bf16_t* w1b = (const bf16_t*)w1tg;
  const bf16_t* w2b = (const bf16_t*)w2tg;

  const int ngr = (E + 15) >> 4;
  const int gw0 = blockIdx.x * 4 + wv;
  const int gstride = gridDim.x * 4;

  for (int g = gw0; g < ngr; g += gstride) {
    long ge = (long)g * 16 + l15;
    bool v = ge < E;

    // ---- A: efeat -> B-fragments direct from global (full K=64 row) ----
    bf16x8 Bf0, Bf1;
    {
      float4 a = {0,0,0,0}, b = a, c = a, d = a;
      if (v) {
        const float4* p = (const float4*)(efeat + ge * 64 + kg * 8);
        a = p[0]; b = p[1];
        const float4* q = (const float4*)(efeat + ge * 64 + 32 + kg * 8);
        c = q[0]; d = q[1];
      }
      Bf0[0]=f2bf(a.x); Bf0[1]=f2bf(a.y); Bf0[2]=f2bf(a.z); Bf0[3]=f2bf(a.w);
      Bf0[4]=f2bf(b.x); Bf0[5]=f2bf(b.y); Bf0[6]=f2bf(b.z); Bf0[7]=f2bf(b.w);
      Bf1[0]=f2bf(c.x); Bf1[1]=f2bf(c.y); Bf1[2]=f2bf(c.z); Bf1[3]=f2bf(c.w);
      Bf1[4]=f2bf(d.x); Bf1[5]=f2bf(d.y); Bf1[6]=f2bf(d.z); Bf1[7]=f2bf(d.w);
    }

    // ---- B: premultiplied TP coefficient table (work split by kg) ----
    //  [0:16) x0 | [16:40) x1*sh0*c11 | [40:48) (x1.sh1)*c10
    //  [48:64) x0*sh0*c00 | [64:67) sh1*c01
    if (v) {
      int dst = eidx[ge];
      const float* xr = atom + (long)dst * 40;
      const float inv_s2 = 0.70710678118654752f;
      if (kg == 0) {
        for (int i = 0; i < 16; ++i) xg[wv][l15][i] = xr[i];
      } else if (kg == 1) {
        float k11 = esh[ge * 4] * inv_s2 * 0.35355339059327378f;
        for (int t2 = 0; t2 < 24; ++t2) xg[wv][l15][16 + t2] = xr[16 + t2] * k11;
      } else if (kg == 2) {
        float s1x = esh[ge * 4 + 1], s1y = esh[ge * 4 + 2], s1z = esh[ge * 4 + 3];
        float k10 = inv_s2 * 0.20412414523193150f;
        for (int i = 0; i < 8; ++i) {
          float y = xr[16 + 3 * i] * s1x + xr[17 + 3 * i] * s1y + xr[18 + 3 * i] * s1z;
          xg[wv][l15][40 + i] = y * k10;
        }
        float ks = inv_s2 * 0.25f;
        xg[wv][l15][64] = s1x * ks;
        xg[wv][l15][65] = s1y * ks;
        xg[wv][l15][66] = s1z * ks;
      } else {
        float k0s = esh[ge * 4] * inv_s2 * 0.25f;
        for (int i = 0; i < 16; ++i) xg[wv][l15][48 + i] = xr[i] * k0s;
      }
    }

    // ---- C: GEMM1  h[j][e] = relu(W1T . ef + b1), all 64 rows ----
    for (int mf = 0; mf < 4; ++mf) {
      const bf16_t* ap = w1b + (16 * mf + l15) * 64;
      bf16x8 a0 = *(const bf16x8*)(ap + kg * 8);
      bf16x8 a1 = *(const bf16x8*)(ap + 32 + kg * 8);
      f32x4 acc = {0.f, 0.f, 0.f, 0.f};
      acc = MFMA16(a0, Bf0, acc);
      acc = MFMA16(a1, Bf1, acc);
      int j0 = 16 * mf + 4 * kg;   // C/D: col=lane&15 (edge), row=(lane>>4)*4+r
      bf16x4 hv;
#pragma unroll
      for (int r = 0; r < 4; ++r) {
        float x = acc[r] + b1[j0 + r];
        x = x > 0.f ? x : 0.f;
        hv[r] = f2bf(x);
      }
      *(bf16x4*)&hlds[wv][l15][j0] = hv;
    }

    // ---- D: re-read h as B-fragments (same wave; lgkmcnt ordering) ----
    bf16x8 Bh0 = *(const bf16x8*)&hlds[wv][l15][kg * 8];
    bf16x8 Bh1 = *(const bf16x8*)&hlds[wv][l15][32 + kg * 8];
    float s0 = xg[wv][l15][64], s1 = xg[wv][l15][65], s2 = xg[wv][l15][66];

    // ---- E: GEMM2 (all 36 w-row blocks) fused with tensor product ----
    float o0[4] = {};        // out0 slice j = 4*kg + r (complete per lane)
    float o1[4][3] = {};     // out1 slice j = 4*(kg&1) + r (partial: this kh)
    for (int mf = 0; mf < 36; ++mf) {
      const bf16_t* ap = w2b + (16 * mf + l15) * 64;
      bf16x8 a0 = *(const bf16x8*)(ap + kg * 8);
      bf16x8 a1 = *(const bf16x8*)(ap + 32 + kg * 8);
      f32x4 bv = *(const f32x4*)&b2[16 * mf + 4 * kg];
      f32x4 acc = {0.f, 0.f, 0.f, 0.f};
      acc = MFMA16(a0, Bh0, acc);
      acc = MFMA16(a1, Bh1, acc);
      if (mf < 16) {                       // w00: i=mf, j=4*kg+r
        float cA = xg[wv][l15][48 + mf];
#pragma unroll
        for (int r = 0; r < 4; ++r) o0[r] += (acc[r] + bv[r]) * cA;
      } else if (mf < 20) {                // w11: i=2*(mf-16)+kh, j=4*(kg&1)+r
        int i = 2 * (mf - 16) + kh;
        float c0 = xg[wv][l15][16 + 3 * i], c1 = xg[wv][l15][17 + 3 * i], c2 = xg[wv][l15][18 + 3 * i];
#pragma unroll
        for (int r = 0; r < 4; ++r) {
          float wA = acc[r] + bv[r];
          o1[r][0] += wA * c0; o1[r][1] += wA * c1; o1[r][2] += wA * c2;
        }
      } else if (mf < 28) {                // w01: i=2*(mf-20)+kh, j=4*(kg&1)+r
        int i = 2 * (mf - 20) + kh;
        float xA = xg[wv][l15][i];
#pragma unroll
        for (int r = 0; r < 4; ++r) {
          float tA = (acc[r] + bv[r]) * xA;
          o1[r][0] += tA * s0; o1[r][1] += tA * s1; o1[r][2] += tA * s2;
        }
      } else {                             // w10: i=mf-28, j=4*kg+r
        float cA = xg[wv][l15][40 + mf - 28];
#pragma unroll
        for (int r = 0; r < 4; ++r) o0[r] += (acc[r] + bv[r]) * cA;
      }
    }
    // fold kh pairs (lane^32: kg<->kg^2, same l15); lanes kg<2 hold full o1
    float o1f[4][3];
#pragma unroll
    for (int r = 0; r < 4; ++r)
#pragma unroll
      for (int c = 0; c < 3; ++c)
        o1f[r][c] = o1[r][c] + __shfl_xor(o1[r][c], 32);

    // ---- F: emit ----
    if (SORTED) {
      // one int ticket per edge (kg==0 lane), broadcast row to kg-partners
      int dstrow = 0;
      if (v && kg == 0) {
        int src = eidx[E + ge];
        dstrow = roff[src] + atomicAdd(&pos[src], 1);
      }
      dstrow = __shfl(dstrow, l15);      // lane l15 holds kg==0's ticket
      if (v) {
        float* orow = outbuf + (long)dstrow * 40;
        f32x4 v0 = {o0[0], o0[1], o0[2], o0[3]};
        *(f32x4*)(orow + 4 * kg) = v0;
        if (kg < 2) {
          f32x4 u0 = {o1f[0][0], o1f[0][1], o1f[0][2], o1f[1][0]};
          f32x4 u1 = {o1f[1][1], o1f[1][2], o1f[2][0], o1f[2][1]};
          f32x4 u2 = {o1f[2][2], o1f[3][0], o1f[3][1], o1f[3][2]};
          float* ob = orow + 16 + 12 * kg;
          *(f32x4*)(ob + 0) = u0;
          *(f32x4*)(ob + 4) = u1;
          *(f32x4*)(ob + 8) = u2;
        }
      }
    } else {
      if (v) {
        int src = eidx[E + ge];
        float* srow = outbuf + (long)src * 40;
#pragma unroll
        for (int r = 0; r < 4; ++r) unsafeAtomicAdd(&srow[4 * kg + r], o0[r]);
        if (kg < 2) {
          int j1 = 4 * kg;
#pragma unroll
          for (int r = 0; r < 4; ++r)
#pragma unroll
            for (int c = 0; c < 3; ++c)
              unsafeAtomicAdd(&srow[16 + 3 * (j1 + r) + c], o1f[r][c]);
        }
      }
    }
  }
}

// -------------------------------------------------------- node (gather) ----
// stats atomics striped over NREP replicas (contention /32) + in-wave 3:1
// vsq fold (8 atomics instead of 24 for v channels).
__global__ __launch_bounds__(256) void tcl_node2(
    const float* __restrict__ atom, const float* __restrict__ tp,
    const int* __restrict__ roff, const int* __restrict__ cnt,
    float* __restrict__ out, float* __restrict__ statsrep, int NN)
{
  int lane = threadIdx.x & 63;
  int gw = blockIdx.x * 4 + (threadIdx.x >> 6);
  int stride = gridDim.x * 4;
  float ssum = 0.f, ssq = 0.f, vsq = 0.f;
  for (int n = gw; n < NN; n += stride) {
    int deg = cnt[n];
    long base = roff[n];
    if (lane < 40) {
      float acc = 0.f;
      for (int d = 0; d < deg; ++d) acc += tp[(base + d) * 40 + lane];
      float c = deg > 0 ? (float)deg : 1.f;
      long idx = (long)n * 40 + lane;
      float o = acc / c + atom[idx];
      out[idx] = o;
      if (lane < 16) { ssum += o; ssq += o * o; }
      else           { vsq += o * o; }
    }
  }
  float* srep = statsrep + (long)(blockIdx.x & (NREP - 1)) * 64;
  // fold 3 vector components in-wave: lane 16+3m collects 16+3m+1, 16+3m+2
  float va = __shfl(vsq, lane + 1);
  float vb = __shfl(vsq, lane + 2);
  if (lane < 16) {
    unsafeAtomicAdd(&srep[lane], ssum);
    unsafeAtomicAdd(&srep[16 + lane], ssq);
  } else if (lane < 40 && (lane - 16) % 3 == 0) {
    unsafeAtomicAdd(&srep[32 + (lane - 16) / 3], (vsq + va) + vb);
  }
}

// ------------------------------------------------------------ collapse ----
__global__ __launch_bounds__(64) void tcl_collapse(
    const float* __restrict__ statsrep, float* __restrict__ statsfin)
{
  int c = threadIdx.x;
  float s = 0.f;
  for (int r = 0; r < NREP; ++r) s += statsrep[(long)r * 64 + c];
  statsfin[c] = s;
}

// ---------------------------------------------------- node (atomic path) ----
__global__ __launch_bounds__(256) void tcl_node(
    const float* __restrict__ atom, const int* __restrict__ cnt,
    float* __restrict__ out, float* __restrict__ stats, int NN)
{
  int lane = threadIdx.x & 63;
  int gw = blockIdx.x * 4 + (threadIdx.x >> 6);
  int stride = gridDim.x * 4;
  float ssum = 0.f, ssq = 0.f, vsq = 0.f;
  for (int r = gw; r < NN; r += stride) {
    float c = (float)cnt[r];
    c = c > 1.f ? c : 1.f;
    if (lane < 40) {
      long idx = (long)r * 40 + lane;
      float o = out[idx] / c + atom[idx];
      out[idx] = o;
      if (lane < 16) { ssum += o; ssq += o * o; }
      else           { vsq += o * o; }
    }
  }
  if (lane < 16) {
    unsafeAtomicAdd(&stats[lane], ssum);
    unsafeAtomicAdd(&stats[16 + lane], ssq);
  } else if (lane < 40) {
    unsafeAtomicAdd(&stats[32 + (lane - 16) / 3], vsq);
  }
}

// ---------------------------------------------------------------- norm ----
__global__ __launch_bounds__(256) void tcl_norm(
    float* __restrict__ out, const float* __restrict__ stats,
    const float* __restrict__ bnw, const float* __restrict__ bnb, int NN)
{
  long idx = (long)blockIdx.x * 256 + threadIdx.x;
  long tot = (long)NN * 40;
  if (idx >= tot) return;
  int c = (int)(idx % 40);
  float o = out[idx];
  float invN = 1.0f / (float)NN;
  if (c < 16) {
    float mean = stats[c] * invN;
    float var  = stats[16 + c] * invN - mean * mean;
    float rs   = rsqrtf(var + 1e-5f);
    o = (o - mean) * rs * bnw[c] + bnb[c];
  } else {
    int m = (c - 16) / 3;
    float vn = stats[32 + m] * invN * (1.0f / 3.0f);
    float rs = rsqrtf(vn + 1e-5f);
    o = o * rs * bnw[16 + m];
  }
  out[idx] = o;
}

// -------------------------------------------------------------- launch ----
extern "C" void kernel_launch(void* const* d_in, const int* in_sizes, int n_in,
                              void* d_out, int out_size, void* d_ws, size_t ws_size,
                              hipStream_t stream)
{
  const float* atom  = (const float*)d_in[0];
  const float* efeat = (const float*)d_in[1];
  const float* esh   = (const float*)d_in[2];
  const int*   eidx  = (const int*)d_in[3];
  const float* w1    = (const float*)d_in[4];
  const float* b1    = (const float*)d_in[5];
  const float* w2    = (const float*)d_in[6];
  const float* b2    = (const float*)d_in[7];
  const float* bnw   = (const float*)d_in[8];
  const float* bnb   = (const float*)d_in[9];
  int E  = in_sizes[3] / 2;
  int NN = in_sizes[0] / 40;
  float* out = (float*)d_out;

  // workspace layout (~81.7MB for E=500k, NN=100k; proven fit in R2/R17)
  size_t off = 0;
  auto align256 = [&](size_t o) { return (o + 255) & ~(size_t)255; };
  int* cnt = (int*)d_ws;                                   off += (size_t)NN * 4;
  off = align256(off);
  int* pos = (int*)((char*)d_ws + off);                    off += (size_t)NN * 4;
  off = align256(off);
  int* excl = (int*)((char*)d_ws + off);                   off += (size_t)NN * 4;
  off = align256(off);
  int* bsum = (int*)((char*)d_ws + off);                   off += 128 * 4;
  off = align256(off);
  int* roff = (int*)((char*)d_ws + off);                   off += (size_t)NN * 4;
  off = align256(off);
  float* statsrep = (float*)((char*)d_ws + off);           off += (size_t)NREP * 64 * 4;
  off = align256(off);
  float* statsfin = (float*)((char*)d_ws + off);           off += 64 * 4;
  off = align256(off);
  unsigned short* w1tg = (unsigned short*)((char*)d_ws + off); off += 64 * 64 * 2;
  off = align256(off);
  unsigned short* w2tg = (unsigned short*)((char*)d_ws + off); off += 576 * 64 * 2;
  off = align256(off);
  float* tp = (float*)((char*)d_ws + off);
  size_t need = off + (size_t)E * 40 * 4;

  int nb = (NN + 1023) / 1024;   // scan chunks (<=128)
  bool sorted = (ws_size >= need) && (nb <= 128);

  tcl_zero<<<(NN + 255) / 256, 256, 0, stream>>>(cnt, pos, statsrep, statsfin, NN);
  tcl_count<<<(E + 255) / 256, 256, 0, stream>>>(eidx, w1, w2, w1tg, w2tg, cnt, E);

  if (sorted) {
    tcl_scan_a<<<nb, 1024, 0, stream>>>(cnt, excl, bsum, NN);
    tcl_scan_b<<<1, 128, 0, stream>>>(bsum, nb);
    tcl_scan_c<<<(NN + 255) / 256, 256, 0, stream>>>(excl, bsum, roff, NN);
    tcl_edge<true><<<2048, 256, 0, stream>>>(atom, efeat, esh, eidx, b1, b2,
                                             w1tg, w2tg, tp, pos, roff, cnt, E);
    tcl_node2<<<1024, 256, 0, stream>>>(atom, tp, roff, cnt, out, statsrep, NN);
    tcl_collapse<<<1, 64, 0, stream>>>(statsrep, statsfin);
  } else {
    hipMemsetAsync(d_out, 0, (size_t)NN * 40 * sizeof(float), stream);
    tcl_edge<false><<<2048, 256, 0, stream>>>(atom, efeat, esh, eidx, b1, b2,
                                              w1tg, w2tg, out, pos, roff, cnt, E);
    tcl_node<<<256, 256, 0, stream>>>(atom, cnt, out, statsfin, NN);
  }
  tcl_norm<<<(int)(((long)NN * 40 + 255) / 256), 256, 0, stream>>>(out, statsfin, bnw, bnb, NN);
}